// Round 7
// baseline (3285.701 us; speedup 1.0000x reference)
//
#include <hip/hip_runtime.h>
#include <hip/hip_bf16.h>
#include <math.h>

#define B_SZ 2048
#define DIN 1024
#define DENC 4096
#define T_ITERS 30

typedef __attribute__((ext_vector_type(8))) short short8;
typedef __attribute__((ext_vector_type(4))) short short4v;
typedef __attribute__((ext_vector_type(4))) float f32x4;

typedef __attribute__((address_space(3))) void lds_void;
typedef const __attribute__((address_space(1))) void glb_void;

__device__ inline short f2bf(float f) {
  union { float f; unsigned u; } v; v.f = f;
  unsigned r = v.u + 0x7fffu + ((v.u >> 16) & 1u);
  return (short)(r >> 16);
}

__device__ inline void gload_lds16(const void* g, void* l) {
  __builtin_amdgcn_global_load_lds((glb_void*)g, (lds_void*)l, 16, 0, 0);
}

template<int N> __device__ inline void waitv() {
  asm volatile("s_waitcnt vmcnt(%0)" :: "n"(N) : "memory");
}

// C[M,N] = A[M,K] * B[N,K]^T  (operands K-contiguous bf16 bits in short)
// NBUF-deep ring-buffer K-loop, counted vmcnt (T4).
// LDS tiles XOR-swizzled (T2): image(row, c') = global(row, c'^(row&3)),
// achieved by pre-swizzling the GLOBAL source (gload_lds dest stays linear,
// rule 21) and XOR-ing the read column. Uniform bank spread -> conflict-free.
// Epilogue staged through LDS for coalesced float4/short4 global RMW.
// MODE 0: OB = bf16(X - acc)                                  (residual r)
// MODE 1: FISTA update. ykv recomputed: ykv = cA*xc + cB*xp (s0: ykv=0).
//         reads XC (= x_{s-1}), XW (= x_{s-2}); writes XW (= x_s), OB (yk bf16)
// MODE 2: XW = acc (final z, f32)
template<int BM, int BN, int K, int MODE, int NBUF>
__global__ __launch_bounds__(256)
void gemm_bt(const short* __restrict__ A, const short* __restrict__ Bm,
             const float* __restrict__ X,    // MODE 0: x input (f32)
             const float* __restrict__ XC,   // MODE 1: x_{s-1}
             float* __restrict__ XW,         // MODE 1: x_{s-2}/x_s; MODE 2: z
             short* __restrict__ OB,         // MODE 0: r_bf16; MODE 1: yk_bf16
             float cA, float cB, float cm, int s0, int last, int Nld)
{
  constexpr int WM = BM / 2;   // wave tile (waves 2x2)
  constexpr int WN = BN / 2;
  constexpr int FM = WM / 16;
  constexpr int FN = WN / 16;
  constexpr int KSTEPS = K / 32;
  constexpr int LPS = (BM + BN) / 64;                  // gload_lds issues per thread per stage
  constexpr int BUF_SHORTS = (BM + BN) * 32;
  constexpr int STAGE_SHORTS = NBUF * BUF_SHORTS;
  constexpr int CT_LD = BN + 4;                        // +4 floats: kill bank conflicts
  constexpr int CT_SHORTS = BM * CT_LD * 2;
  constexpr int SMEM_SHORTS = CT_SHORTS > STAGE_SHORTS ? CT_SHORTS : STAGE_SHORTS;

  __shared__ __align__(16) short smem[SMEM_SHORTS];

  const int tid  = threadIdx.x;
  const int lane = tid & 63;
  const int w    = tid >> 6;
  const int wm   = w >> 1, wn = w & 1;
  const long a_row0 = (long)blockIdx.y * BM;
  const long b_row0 = (long)blockIdx.x * BN;

  // LDS ring: buf b = [A tile BM*32 | B tile BN*32]
  auto asp = [&](int buf) -> short* { return smem + buf * BUF_SHORTS; };
  auto bsp = [&](int buf) -> short* { return smem + buf * BUF_SHORTS + BM * 32; };

  auto stage = [&](int buf, int kt) {
    const int k0 = kt * 32;
    short* ap = asp(buf);
    short* bp = bsp(buf);
#pragma unroll
    for (int rr = 0; rr < BM / 64; ++rr) {
      int idx16 = rr * 256 + tid;
      int row = idx16 >> 2;
      int ce = ((idx16 & 3) ^ (row & 3)) * 8;     // pre-swizzled global source
      gload_lds16(A + (a_row0 + row) * K + k0 + ce,
                  ap + (rr * 256 + (tid & 192)) * 8);
    }
#pragma unroll
    for (int rr = 0; rr < BN / 64; ++rr) {
      int idx16 = rr * 256 + tid;
      int row = idx16 >> 2;
      int ce = ((idx16 & 3) ^ (row & 3)) * 8;     // pre-swizzled global source
      gload_lds16(Bm + (b_row0 + row) * K + k0 + ce,
                  bp + (rr * 256 + (tid & 192)) * 8);
    }
  };

  f32x4 acc[FM][FN];
#pragma unroll
  for (int i = 0; i < FM; ++i)
#pragma unroll
    for (int j = 0; j < FN; ++j) acc[i][j] = (f32x4){0.f, 0.f, 0.f, 0.f};

  // prologue: fill NBUF-1 buffers
#pragma unroll
  for (int p = 0; p < NBUF - 1; ++p) stage(p, p);

  for (int kt = 0; kt < KSTEPS; ++kt) {
    __syncthreads();   // all waves done reading buf[(kt-1)%NBUF] (the stage target)
    if (kt + NBUF - 1 < KSTEPS) stage((kt + NBUF - 1) % NBUF, kt + NBUF - 1);
    const int rem = KSTEPS - 1 - kt;   // tiles still in flight beyond kt
    if constexpr (NBUF >= 4) {
      if (rem >= 3)      waitv<3 * LPS>();
      else if (rem == 2) waitv<2 * LPS>();
      else if (rem == 1) waitv<1 * LPS>();
      else               waitv<0>();
    } else {
      if (rem >= 2)      waitv<2 * LPS>();
      else if (rem == 1) waitv<1 * LPS>();
      else               waitv<0>();
    }
    __syncthreads();   // tile kt visible to all waves

    const short* ap = asp(kt % NBUF);
    const short* bp = bsp(kt % NBUF);
    short8 af[FM], bfr[FN];
#pragma unroll
    for (int i = 0; i < FM; ++i) {
      int row = wm * WM + i * 16 + (lane & 15);
      af[i] = *(const short8*)(ap + row * 32 + (((lane >> 4) ^ (row & 3)) * 8));
    }
#pragma unroll
    for (int j = 0; j < FN; ++j) {
      int row = wn * WN + j * 16 + (lane & 15);
      bfr[j] = *(const short8*)(bp + row * 32 + (((lane >> 4) ^ (row & 3)) * 8));
    }
#pragma unroll
    for (int i = 0; i < FM; ++i)
#pragma unroll
      for (int j = 0; j < FN; ++j)
        acc[i][j] = __builtin_amdgcn_mfma_f32_16x16x32_bf16(af[i], bfr[j], acc[i][j], 0, 0, 0);
  }
  __syncthreads();

  // ---- epilogue: acc -> LDS (padded), then coalesced vector RMW ----
  float* ct = (float*)smem;   // staging buffers dead after final barrier
  const int rbase = wm * WM + ((lane >> 4) << 2);
  const int cbase = wn * WN + (lane & 15);
#pragma unroll
  for (int i = 0; i < FM; ++i)
#pragma unroll
    for (int j = 0; j < FN; ++j)
#pragma unroll
      for (int r = 0; r < 4; ++r)
        ct[(rbase + i * 16 + r) * CT_LD + cbase + j * 16] = acc[i][j][r];
  __syncthreads();

  constexpr int QITER = (BM * BN) / 1024;   // 256 threads x 4 floats per pass
#pragma unroll
  for (int q = 0; q < QITER; ++q) {
    const int flat = q * 1024 + tid * 4;
    const int row = flat / BN, col = flat % BN;
    const f32x4 cv = *(const f32x4*)(ct + row * CT_LD + col);
    const long gidx = (a_row0 + row) * (long)Nld + (b_row0 + col);

    if (MODE == 0) {
      const f32x4 xv = *(const f32x4*)(X + gidx);
      short4v rb;
#pragma unroll
      for (int e = 0; e < 4; ++e) rb[e] = f2bf(xv[e] - cv[e]);
      *(short4v*)(OB + gidx) = rb;
    } else if (MODE == 2) {
      *(f32x4*)(XW + gidx) = cv;
    } else {
      f32x4 xc4 = (f32x4){0.f, 0.f, 0.f, 0.f};
      f32x4 xp4 = (f32x4){0.f, 0.f, 0.f, 0.f};
      if (!s0) { xc4 = *(const f32x4*)(XC + gidx); xp4 = *(const f32x4*)(XW + gidx); }
      f32x4 xn4; short4v yb;
#pragma unroll
      for (int e = 0; e < 4; ++e) {
        float ykv = cA * xc4[e] + cB * xp4[e];     // yk_s recomputed (0 at s=0)
        float xg  = ykv + cv[e] * 0.1f;            // yk + H^T r / L
        float s   = fabsf(xg) - 0.01f;             // lam / L
        float xn  = s > 0.f ? copysignf(s, xg) : 0.f;
        float xo  = xc4[e];                        // x_old = x_{s-1} (0 at s=0)
        float yn  = xn + cm * (xn - xo);
        xn4[e] = xn;
        yb[e]  = f2bf(last ? xn : yn);
      }
      *(f32x4*)(XW + gidx) = xn4;                  // x_s (ping-pong, same idx read above)
      *(short4v*)(OB + gidx) = yb;                 // yk_{s+1} bf16 operand
    }
  }
}

// pack H (f32 [DIN,DENC]) -> Hbf [DIN,DENC] bf16 and Htbf [DENC,DIN] bf16
__global__ void pack_H_kernel(const float* __restrict__ H, short* __restrict__ Hbf,
                              short* __restrict__ Htbf) {
  __shared__ float tile[32][33];
  int tx = threadIdx.x, ty0 = threadIdx.y;
  int j0 = blockIdx.x * 32;  // DENC
  int i0 = blockIdx.y * 32;  // DIN
#pragma unroll
  for (int r = 0; r < 4; ++r) {
    int ty = ty0 * 4 + r;
    float v = H[(long)(i0 + ty) * DENC + j0 + tx];
    tile[ty][tx] = v;
    Hbf[(long)(i0 + ty) * DENC + j0 + tx] = f2bf(v);
  }
  __syncthreads();
#pragma unroll
  for (int r = 0; r < 4; ++r) {
    int ty = ty0 * 4 + r;
    Htbf[(long)(j0 + ty) * DIN + i0 + tx] = f2bf(tile[tx][ty]);
  }
}

extern "C" void kernel_launch(void* const* d_in, const int* in_sizes, int n_in,
                              void* d_out, int out_size, void* d_ws, size_t ws_size,
                              hipStream_t stream) {
  const float* x = (const float*)d_in[0];  // [2048,1024]
  const float* H = (const float*)d_in[1];  // [1024,4096]

  float* z_out = (float*)d_out;                       // [2048,1024]
  float* xB    = (float*)d_out + (size_t)B_SZ * DIN;  // buf1: x_s for odd s (= final x_new)

  char* ws = (char*)d_ws;
  size_t off = 0;
  float* xA   = (float*)(ws + off); off += (size_t)B_SZ * DENC * 4;  // buf0: x_s for even s
  short* ykbf = (short*)(ws + off); off += (size_t)B_SZ * DENC * 2;  // 16 MB
  short* rbf  = (short*)(ws + off); off += (size_t)B_SZ * DIN  * 2;  //  4 MB
  short* Hbf  = (short*)(ws + off); off += (size_t)DIN  * DENC * 2;  //  8 MB
  short* Htbf = (short*)(ws + off);                                  //  8 MB

  hipMemsetAsync(ykbf, 0, (size_t)B_SZ * DENC * 2, stream);          // yk_0 = 0
  pack_H_kernel<<<dim3(DENC / 32, DIN / 32), dim3(32, 8), 0, stream>>>(H, Hbf, Htbf);

  double t = 1.0, cprev = 0.0;
  for (int s = 0; s < T_ITERS; ++s) {
    // r = x - yk @ H^T : M=2048 N=1024 K=4096 (128x64 tile, 256 blocks, NBUF=4)
    gemm_bt<128, 64, DENC, 0, 4><<<dim3(DIN / 64, B_SZ / 128), 256, 0, stream>>>(
        ykbf, Hbf, x, nullptr, nullptr, rbf, 0.f, 0.f, 0.f, 0, 0, DIN);
    double tn = (1.0 + sqrt(1.0 + 4.0 * t * t)) * 0.5;
    float cs = (float)((t - 1.0) / tn);
    // x_s -> buf[s&1]; reads xc = x_{s-1} from buf[(s-1)&1], xp = x_{s-2} from buf[s&1]
    const float* xc = (s & 1) ? xA : (const float*)xB;
    float* xw       = (s & 1) ? xB : xA;
    if (s == 0) xc = xB;  // unused at s=0 (s0 flag)
    // g = r @ H ; fused FISTA update : M=2048 N=4096 K=1024 (1024 blocks, NBUF=3)
    gemm_bt<64, 128, DIN, 1, 3><<<dim3(DENC / 128, B_SZ / 64), 256, 0, stream>>>(
        rbf, Htbf, nullptr, xc, xw, ykbf,
        (float)(1.0 + cprev), (float)(-cprev), cs, (s == 0) ? 1 : 0,
        (s == T_ITERS - 1) ? 1 : 0, DENC);
    cprev = cs; t = tn;
  }
  // z = x_new @ H^T : M=2048 N=1024 K=4096 (ykbf holds bf16(x_29))
  gemm_bt<128, 64, DENC, 2, 4><<<dim3(DIN / 64, B_SZ / 128), 256, 0, stream>>>(
      ykbf, Hbf, nullptr, nullptr, z_out, nullptr, 0.f, 0.f, 0.f, 0, 0, DIN);
}

// Round 8
// 2390.306 us; speedup vs baseline: 1.3746x; 1.3746x over previous
//
#include <hip/hip_runtime.h>
#include <hip/hip_bf16.h>
#include <math.h>

#define B_SZ 2048
#define DIN 1024
#define DENC 4096
#define T_ITERS 30

typedef __attribute__((ext_vector_type(8))) short short8;
typedef __attribute__((ext_vector_type(4))) short short4v;
typedef __attribute__((ext_vector_type(4))) float f32x4;

typedef __attribute__((address_space(3))) void lds_void;
typedef const __attribute__((address_space(1))) void glb_void;

__device__ inline short f2bf(float f) {
  union { float f; unsigned u; } v; v.f = f;
  unsigned r = v.u + 0x7fffu + ((v.u >> 16) & 1u);
  return (short)(r >> 16);
}

__device__ inline void gload_lds16(const void* g, void* l) {
  __builtin_amdgcn_global_load_lds((glb_void*)g, (lds_void*)l, 16, 0, 0);
}

template<int N> __device__ inline void waitv() {
  asm volatile("s_waitcnt vmcnt(%0)" :: "n"(N) : "memory");
}

// Raw workgroup barrier WITHOUT the vmcnt(0) drain that __syncthreads()
// implies (the drain defeats counted-vmcnt pipelining; guide §5 m97/m201).
// Compiler-only fences stop LDS ops migrating across it.
__device__ inline void barrier_raw() {
  asm volatile("" ::: "memory");
  __builtin_amdgcn_s_barrier();
  asm volatile("" ::: "memory");
}

// C[M,N] = A[M,K] * B[N,K]^T  (operands K-contiguous bf16 bits in short)
// NBUF-deep ring-buffer K-loop, counted vmcnt (T4) + RAW barriers so the
// prefetched global_load_lds stay in flight across K-steps.
// Epilogue staged through LDS for coalesced float4/short4 global RMW.
// MODE 0: OB = bf16(X - acc)                                  (residual r)
// MODE 1: FISTA update. ykv recomputed: ykv = cA*xc + cB*xp (s0: ykv=0).
//         reads XC (= x_{s-1}), XW (= x_{s-2}); writes XW (= x_s), OB (yk bf16)
// MODE 2: XW = acc (final z, f32)
template<int BM, int BN, int K, int MODE, int NBUF>
__global__ __launch_bounds__(256)
void gemm_bt(const short* __restrict__ A, const short* __restrict__ Bm,
             const float* __restrict__ X,    // MODE 0: x input (f32)
             const float* __restrict__ XC,   // MODE 1: x_{s-1}
             float* __restrict__ XW,         // MODE 1: x_{s-2}/x_s; MODE 2: z
             short* __restrict__ OB,         // MODE 0: r_bf16; MODE 1: yk_bf16
             float cA, float cB, float cm, int s0, int last, int Nld)
{
  constexpr int WM = BM / 2;   // wave tile (waves 2x2)
  constexpr int WN = BN / 2;
  constexpr int FM = WM / 16;
  constexpr int FN = WN / 16;
  constexpr int KSTEPS = K / 32;
  constexpr int LPS = (BM + BN) / 64;                  // gload_lds issues per thread per stage
  constexpr int BUF_SHORTS = (BM + BN) * 32;
  constexpr int STAGE_SHORTS = NBUF * BUF_SHORTS;
  constexpr int CT_LD = BN + 4;                        // +4 floats: kill bank conflicts
  constexpr int CT_SHORTS = BM * CT_LD * 2;
  constexpr int SMEM_SHORTS = CT_SHORTS > STAGE_SHORTS ? CT_SHORTS : STAGE_SHORTS;

  __shared__ __align__(16) short smem[SMEM_SHORTS];

  const int tid  = threadIdx.x;
  const int lane = tid & 63;
  const int w    = tid >> 6;
  const int wm   = w >> 1, wn = w & 1;
  const long a_row0 = (long)blockIdx.y * BM;
  const long b_row0 = (long)blockIdx.x * BN;

  // LDS ring: buf b = [A tile BM*32 | B tile BN*32]
  auto asp = [&](int buf) -> short* { return smem + buf * BUF_SHORTS; };
  auto bsp = [&](int buf) -> short* { return smem + buf * BUF_SHORTS + BM * 32; };

  auto stage = [&](int buf, int kt) {
    const int k0 = kt * 32;
    short* ap = asp(buf);
    short* bp = bsp(buf);
#pragma unroll
    for (int rr = 0; rr < BM / 64; ++rr) {
      int idx16 = rr * 256 + tid;
      int row = idx16 >> 2, ce = (idx16 & 3) * 8;
      gload_lds16(A + (a_row0 + row) * K + k0 + ce,
                  ap + (rr * 256 + (tid & 192)) * 8);
    }
#pragma unroll
    for (int rr = 0; rr < BN / 64; ++rr) {
      int idx16 = rr * 256 + tid;
      int row = idx16 >> 2, ce = (idx16 & 3) * 8;
      gload_lds16(Bm + (b_row0 + row) * K + k0 + ce,
                  bp + (rr * 256 + (tid & 192)) * 8);
    }
  };

  f32x4 acc[FM][FN];
#pragma unroll
  for (int i = 0; i < FM; ++i)
#pragma unroll
    for (int j = 0; j < FN; ++j) acc[i][j] = (f32x4){0.f, 0.f, 0.f, 0.f};

  // prologue: fill NBUF-1 buffers
#pragma unroll
  for (int p = 0; p < NBUF - 1; ++p) stage(p, p);

  for (int kt = 0; kt < KSTEPS; ++kt) {
    barrier_raw();     // all waves done reading buf[(kt-1)%NBUF] (the stage target)
    if (kt + NBUF - 1 < KSTEPS) stage((kt + NBUF - 1) % NBUF, kt + NBUF - 1);
    const int rem = KSTEPS - 1 - kt;   // tiles still in flight beyond kt
    if constexpr (NBUF >= 4) {
      if (rem >= 3)      waitv<3 * LPS>();
      else if (rem == 2) waitv<2 * LPS>();
      else if (rem == 1) waitv<1 * LPS>();
      else               waitv<0>();
    } else {
      if (rem >= 2)      waitv<2 * LPS>();
      else if (rem == 1) waitv<1 * LPS>();
      else               waitv<0>();
    }
    barrier_raw();     // tile kt visible to all waves (others' loads counted too)

    const short* ap = asp(kt % NBUF);
    const short* bp = bsp(kt % NBUF);
    short8 af[FM], bfr[FN];
#pragma unroll
    for (int i = 0; i < FM; ++i) {
      int row = wm * WM + i * 16 + (lane & 15);
      af[i] = *(const short8*)(ap + row * 32 + (lane >> 4) * 8);
    }
#pragma unroll
    for (int j = 0; j < FN; ++j) {
      int row = wn * WN + j * 16 + (lane & 15);
      bfr[j] = *(const short8*)(bp + row * 32 + (lane >> 4) * 8);
    }
#pragma unroll
    for (int i = 0; i < FM; ++i)
#pragma unroll
      for (int j = 0; j < FN; ++j)
        acc[i][j] = __builtin_amdgcn_mfma_f32_16x16x32_bf16(af[i], bfr[j], acc[i][j], 0, 0, 0);
  }
  __syncthreads();   // full drain before smem reuse

  // ---- epilogue: acc -> LDS (padded), then coalesced vector RMW ----
  float* ct = (float*)smem;   // staging buffers dead after final barrier
  const int rbase = wm * WM + ((lane >> 4) << 2);
  const int cbase = wn * WN + (lane & 15);
#pragma unroll
  for (int i = 0; i < FM; ++i)
#pragma unroll
    for (int j = 0; j < FN; ++j)
#pragma unroll
      for (int r = 0; r < 4; ++r)
        ct[(rbase + i * 16 + r) * CT_LD + cbase + j * 16] = acc[i][j][r];
  __syncthreads();

  constexpr int QITER = (BM * BN) / 1024;   // 256 threads x 4 floats per pass
#pragma unroll
  for (int q = 0; q < QITER; ++q) {
    const int flat = q * 1024 + tid * 4;
    const int row = flat / BN, col = flat % BN;
    const f32x4 cv = *(const f32x4*)(ct + row * CT_LD + col);
    const long gidx = (a_row0 + row) * (long)Nld + (b_row0 + col);

    if (MODE == 0) {
      const f32x4 xv = *(const f32x4*)(X + gidx);
      short4v rb;
#pragma unroll
      for (int e = 0; e < 4; ++e) rb[e] = f2bf(xv[e] - cv[e]);
      *(short4v*)(OB + gidx) = rb;
    } else if (MODE == 2) {
      *(f32x4*)(XW + gidx) = cv;
    } else {
      f32x4 xc4 = (f32x4){0.f, 0.f, 0.f, 0.f};
      f32x4 xp4 = (f32x4){0.f, 0.f, 0.f, 0.f};
      if (!s0) { xc4 = *(const f32x4*)(XC + gidx); xp4 = *(const f32x4*)(XW + gidx); }
      f32x4 xn4; short4v yb;
#pragma unroll
      for (int e = 0; e < 4; ++e) {
        float ykv = cA * xc4[e] + cB * xp4[e];     // yk_s recomputed (0 at s=0)
        float xg  = ykv + cv[e] * 0.1f;            // yk + H^T r / L
        float s   = fabsf(xg) - 0.01f;             // lam / L
        float xn  = s > 0.f ? copysignf(s, xg) : 0.f;
        float xo  = xc4[e];                        // x_old = x_{s-1} (0 at s=0)
        float yn  = xn + cm * (xn - xo);
        xn4[e] = xn;
        yb[e]  = f2bf(last ? xn : yn);
      }
      *(f32x4*)(XW + gidx) = xn4;                  // x_s (ping-pong, same idx read above)
      *(short4v*)(OB + gidx) = yb;                 // yk_{s+1} bf16 operand
    }
  }
}

// pack H (f32 [DIN,DENC]) -> Hbf [DIN,DENC] bf16 and Htbf [DENC,DIN] bf16
__global__ void pack_H_kernel(const float* __restrict__ H, short* __restrict__ Hbf,
                              short* __restrict__ Htbf) {
  __shared__ float tile[32][33];
  int tx = threadIdx.x, ty0 = threadIdx.y;
  int j0 = blockIdx.x * 32;  // DENC
  int i0 = blockIdx.y * 32;  // DIN
#pragma unroll
  for (int r = 0; r < 4; ++r) {
    int ty = ty0 * 4 + r;
    float v = H[(long)(i0 + ty) * DENC + j0 + tx];
    tile[ty][tx] = v;
    Hbf[(long)(i0 + ty) * DENC + j0 + tx] = f2bf(v);
  }
  __syncthreads();
#pragma unroll
  for (int r = 0; r < 4; ++r) {
    int ty = ty0 * 4 + r;
    Htbf[(long)(j0 + ty) * DIN + i0 + tx] = f2bf(tile[tx][ty]);
  }
}

extern "C" void kernel_launch(void* const* d_in, const int* in_sizes, int n_in,
                              void* d_out, int out_size, void* d_ws, size_t ws_size,
                              hipStream_t stream) {
  const float* x = (const float*)d_in[0];  // [2048,1024]
  const float* H = (const float*)d_in[1];  // [1024,4096]

  float* z_out = (float*)d_out;                       // [2048,1024]
  float* xB    = (float*)d_out + (size_t)B_SZ * DIN;  // buf1: x_s for odd s (= final x_new)

  char* ws = (char*)d_ws;
  size_t off = 0;
  float* xA   = (float*)(ws + off); off += (size_t)B_SZ * DENC * 4;  // buf0: x_s for even s
  short* ykbf = (short*)(ws + off); off += (size_t)B_SZ * DENC * 2;  // 16 MB
  short* rbf  = (short*)(ws + off); off += (size_t)B_SZ * DIN  * 2;  //  4 MB
  short* Hbf  = (short*)(ws + off); off += (size_t)DIN  * DENC * 2;  //  8 MB
  short* Htbf = (short*)(ws + off);                                  //  8 MB

  hipMemsetAsync(ykbf, 0, (size_t)B_SZ * DENC * 2, stream);          // yk_0 = 0
  pack_H_kernel<<<dim3(DENC / 32, DIN / 32), dim3(32, 8), 0, stream>>>(H, Hbf, Htbf);

  double t = 1.0, cprev = 0.0;
  for (int s = 0; s < T_ITERS; ++s) {
    // r = x - yk @ H^T : M=2048 N=1024 K=4096 (128x64 tile, 256 blocks, NBUF=4)
    gemm_bt<128, 64, DENC, 0, 4><<<dim3(DIN / 64, B_SZ / 128), 256, 0, stream>>>(
        ykbf, Hbf, x, nullptr, nullptr, rbf, 0.f, 0.f, 0.f, 0, 0, DIN);
    double tn = (1.0 + sqrt(1.0 + 4.0 * t * t)) * 0.5;
    float cs = (float)((t - 1.0) / tn);
    // x_s -> buf[s&1]; reads xc = x_{s-1} from buf[(s-1)&1], xp = x_{s-2} from buf[s&1]
    const float* xc = (s & 1) ? xA : (const float*)xB;
    float* xw       = (s & 1) ? xB : xA;
    if (s == 0) xc = xB;  // unused at s=0 (s0 flag)
    // g = r @ H ; fused FISTA update : M=2048 N=4096 K=1024 (1024 blocks, NBUF=3)
    gemm_bt<64, 128, DIN, 1, 3><<<dim3(DENC / 128, B_SZ / 64), 256, 0, stream>>>(
        rbf, Htbf, nullptr, xc, xw, ykbf,
        (float)(1.0 + cprev), (float)(-cprev), cs, (s == 0) ? 1 : 0,
        (s == T_ITERS - 1) ? 1 : 0, DENC);
    cprev = cs; t = tn;
  }
  // z = x_new @ H^T : M=2048 N=1024 K=4096 (ykbf holds bf16(x_29))
  gemm_bt<128, 64, DENC, 2, 4><<<dim3(DIN / 64, B_SZ / 128), 256, 0, stream>>>(
      ykbf, Hbf, nullptr, nullptr, z_out, nullptr, 0.f, 0.f, 0.f, 0, 0, DIN);
}